// Round 1
// 510.369 us; speedup vs baseline: 1.0419x; 1.0419x over previous
//
#include <hip/hip_runtime.h>
#include <math.h>

#define DM 3136
#define DH 512

typedef __attribute__((ext_vector_type(8))) short bf16x8;
typedef __attribute__((ext_vector_type(4))) float f32x4;

__device__ __forceinline__ ushort f2bf(float f) {
  union { float f; unsigned u; } v; v.f = f;
  unsigned r = v.u + 0x7FFFu + ((v.u >> 16) & 1u);
  return (ushort)(r >> 16);
}

#define MICRO_4x4 \
    acc[0][0] += a.x*b.x; acc[0][1] += a.x*b.y; acc[0][2] += a.x*b.z; acc[0][3] += a.x*b.w; \
    acc[1][0] += a.y*b.x; acc[1][1] += a.y*b.y; acc[1][2] += a.y*b.z; acc[1][3] += a.y*b.w; \
    acc[2][0] += a.z*b.x; acc[2][1] += a.z*b.y; acc[2][2] += a.z*b.z; acc[2][3] += a.z*b.w; \
    acc[3][0] += a.w*b.x; acc[3][1] += a.w*b.y; acc[3][2] += a.w*b.z; acc[3][3] += a.w*b.w;

// ---------------- gelu ----------------
__device__ __forceinline__ void gelu_both(float xx, float& g, float& gp) {
  const float c = 0.7978845608028654f;
  const float a = 0.044715f;
  float x2 = xx * xx;
  float u = c * (xx + a * xx * x2);
  float t = tanhf(u);
  g  = 0.5f * xx * (1.f + t);
  gp = 0.5f * (1.f + t) + 0.5f * xx * (1.f - t * t) * c * (1.f + 3.f * a * x2);
}
__device__ __forceinline__ float gelu_only(float xx) {
  const float c = 0.7978845608028654f;
  const float a = 0.044715f;
  float u = c * (xx + a * xx * xx * xx);
  return 0.5f * xx * (1.f + tanhf(u));
}

// ---------------- conv3x3 + RMSNorm (nk now bf16) + W1 transpose tail ----------------
__global__ __launch_bounds__(256) void conv_rms(
    const float* __restrict__ x,
    const float* __restrict__ wk, const float* __restrict__ bk,
    const float* __restrict__ wv, const float* __restrict__ bv,
    const float* __restrict__ sk, const float* __restrict__ sv,
    const float* __restrict__ W1, ushort* __restrict__ w1tb,
    ushort* __restrict__ nkb, float* __restrict__ nv) {
  __shared__ float smem[4160];   // transpose path: 64x65; conv path: uses first 304
  if (blockIdx.x >= 1568) {
    // transpose W1 [3136,512] f32 -> w1tb [512,3136] bf16, one 64x64 tile per block
    int t = blockIdx.x - 1568;           // 0..391
    int d0 = (t % 49) * 64, h0 = (t / 49) * 64;
    int tid = threadIdx.x;
    int c = tid & 63, rq = tid >> 6;
    #pragma unroll
    for (int q = 0; q < 16; ++q) {
      int r = q * 4 + rq;
      smem[r * 65 + c] = W1[(size_t)(d0 + r) * 512 + h0 + c];
    }
    __syncthreads();
    #pragma unroll
    for (int q = 0; q < 16; ++q) {
      int r = q * 4 + rq;
      w1tb[(size_t)(h0 + r) * 3136 + d0 + c] = f2bf(smem[c * 65 + r]);
    }
    return;
  }
  float* swk = smem;
  float* swv = smem + 144;
  float* sb  = smem + 288;
  int tid = threadIdx.x;
  if (tid < 144) { swk[tid] = wk[tid]; swv[tid] = wv[tid]; }
  if (tid < 4) {
    sb[tid] = bk[tid]; sb[4 + tid] = bv[tid];
    sb[8 + tid] = sk[tid]; sb[12 + tid] = sv[tid];
  }
  __syncthreads();
  int idx = blockIdx.x * 256 + tid;
  int t = idx / 784, hw = idx - t * 784;
  int h = hw / 28, w = hw - h * 28;
  float ak[4], av[4];
  #pragma unroll
  for (int c = 0; c < 4; ++c) { ak[c] = sb[c]; av[c] = sb[4 + c]; }
  const float* xt = x + (size_t)t * DM;
  for (int kh = 0; kh < 3; ++kh) {
    int ih = h + kh - 1;
    if (ih < 0 || ih >= 28) continue;
    for (int kw = 0; kw < 3; ++kw) {
      int iw = w + kw - 1;
      if (iw < 0 || iw >= 28) continue;
      int base = (kh * 3 + kw) * 16;
      #pragma unroll
      for (int ci = 0; ci < 4; ++ci) {
        float xv = xt[ci * 784 + ih * 28 + iw];
        #pragma unroll
        for (int co = 0; co < 4; ++co) {
          ak[co] += xv * swk[base + ci * 4 + co];
          av[co] += xv * swv[base + ci * 4 + co];
        }
      }
    }
  }
  float mk = (ak[0]*ak[0] + ak[1]*ak[1] + ak[2]*ak[2] + ak[3]*ak[3]) * 0.25f + 1e-6f;
  float mv = (av[0]*av[0] + av[1]*av[1] + av[2]*av[2] + av[3]*av[3]) * 0.25f + 1e-6f;
  float ik = 1.f / sqrtf(mk), iv = 1.f / sqrtf(mv);
  ushort4 ok = { f2bf(ak[0]*ik*sb[8]), f2bf(ak[1]*ik*sb[9]),
                 f2bf(ak[2]*ik*sb[10]), f2bf(ak[3]*ik*sb[11]) };
  float4 ov = { av[0]*iv*sb[12], av[1]*iv*sb[13], av[2]*iv*sb[14], av[3]*iv*sb[15] };
  *(ushort4*)&nkb[(size_t)idx * 4] = ok;
  *(float4*)&nv[(size_t)idx * 4] = ov;
}

// ---------------- mm_nn: A[64,K]@B tile -> slice (proven R7) ----------------
__device__ __forceinline__ void mm_nn_slice(
    const float* __restrict__ A, int lda, const float* __restrict__ B, int ldb,
    float* __restrict__ Cp, int ldc, int n_t, int k_t, float* smem) {
  float* As = smem;
  float* Bs = smem + 4096;
  int tid = threadIdx.x;
  int n0 = n_t * 64, k0 = k_t * 64;
  {
    int m  = tid >> 2;
    int kb = (tid & 3) * 16;
    const float* Ap = A + (size_t)m * lda + k0 + kb;
    #pragma unroll
    for (int q = 0; q < 4; ++q) {
      float4 v = *(const float4*)(Ap + q * 4);
      As[(kb + q*4 + 0)*64 + m] = v.x;
      As[(kb + q*4 + 1)*64 + m] = v.y;
      As[(kb + q*4 + 2)*64 + m] = v.z;
      As[(kb + q*4 + 3)*64 + m] = v.w;
    }
    int kr = tid >> 4;
    int nn = (tid & 15) * 4;
    #pragma unroll
    for (int q = 0; q < 4; ++q)
      *(float4*)&Bs[(kr + q*16)*64 + nn] = *(const float4*)(B + (size_t)(k0 + kr + q*16) * ldb + n0 + nn);
  }
  __syncthreads();
  int tx = tid & 15, ty = tid >> 4;
  float acc[4][4] = {{0.f}};
  #pragma unroll 16
  for (int kk = 0; kk < 64; ++kk) {
    float4 a = *(const float4*)&As[kk*64 + ty * 4];
    float4 b = *(const float4*)&Bs[kk*64 + tx * 4];
    MICRO_4x4
  }
  float* Cb = Cp + (size_t)k_t * 64 * ldc + n0 + tx * 4;
  #pragma unroll
  for (int r = 0; r < 4; ++r) {
    float4 v = { acc[r][0], acc[r][1], acc[r][2], acc[r][3] };
    *(float4*)&Cb[(size_t)(ty * 4 + r) * ldc] = v;
  }
}

// ---------------- mm_nt: A[64,K]@B^T (B [N,K] rows) (proven R7) ----------------
__device__ __forceinline__ void mm_nt_slice(
    const float* __restrict__ A, int lda, const float* __restrict__ B, int ldb,
    float* __restrict__ Cp, int ldc, int n_t, int k_t, float* smem) {
  float* As = smem;
  float* Bs = smem + 4096;
  int tid = threadIdx.x;
  int n0 = n_t * 64, k0 = k_t * 64;
  {
    int m  = tid >> 2;
    int kb = (tid & 3) * 16;
    const float* Ap = A + (size_t)m * lda + k0 + kb;
    const float* Bp = B + (size_t)(n0 + m) * ldb + k0 + kb;
    #pragma unroll
    for (int q = 0; q < 4; ++q) {
      float4 va = *(const float4*)(Ap + q * 4);
      As[(kb + q*4 + 0)*64 + m] = va.x;
      As[(kb + q*4 + 1)*64 + m] = va.y;
      As[(kb + q*4 + 2)*64 + m] = va.z;
      As[(kb + q*4 + 3)*64 + m] = va.w;
      float4 vb = *(const float4*)(Bp + q * 4);
      Bs[(kb + q*4 + 0)*64 + m] = vb.x;
      Bs[(kb + q*4 + 1)*64 + m] = vb.y;
      Bs[(kb + q*4 + 2)*64 + m] = vb.z;
      Bs[(kb + q*4 + 3)*64 + m] = vb.w;
    }
  }
  __syncthreads();
  int tx = tid & 15, ty = tid >> 4;
  float acc[4][4] = {{0.f}};
  #pragma unroll 16
  for (int kk = 0; kk < 64; ++kk) {
    float4 a = *(const float4*)&As[kk*64 + ty * 4];
    float4 b = *(const float4*)&Bs[kk*64 + tx * 4];
    MICRO_4x4
  }
  float* Cb = Cp + (size_t)k_t * 64 * ldc + n0 + tx * 4;
  #pragma unroll
  for (int r = 0; r < 4; ++r) {
    float4 v = { acc[r][0], acc[r][1], acc[r][2], acc[r][3] };
    *(float4*)&Cb[(size_t)(ty * 4 + r) * ldc] = v;
  }
}

// ---------------- upd64: Cnew = Cold - A^T B (proven R3/R7) ----------------
__device__ __forceinline__ void upd64_dev(
    const float* __restrict__ A, int P,
    const float* __restrict__ B, int Q,
    const float* __restrict__ Cold, float* __restrict__ Cnew,
    int bx, int by, float* smem) {
  float* As = smem;
  float* Bs = smem + 4096;
  int tid = threadIdx.x;
  int q0 = bx * 64;
  int p0 = by * 64;
  {
    int i = tid >> 4;
    int c = (tid & 15) * 4;
    #pragma unroll
    for (int q = 0; q < 4; ++q) {
      *(float4*)&As[(i + q*16)*64 + c] = *(const float4*)(A + (size_t)(i + q*16) * P + p0 + c);
      *(float4*)&Bs[(i + q*16)*64 + c] = *(const float4*)(B + (size_t)(i + q*16) * Q + q0 + c);
    }
  }
  __syncthreads();
  int tx = tid & 15, ty = tid >> 4;
  float acc[4][4] = {{0.f}};
  #pragma unroll 16
  for (int i = 0; i < 64; ++i) {
    float4 a = *(const float4*)&As[i*64 + ty * 4];
    float4 b = *(const float4*)&Bs[i*64 + tx * 4];
    MICRO_4x4
  }
  #pragma unroll
  for (int r = 0; r < 4; ++r) {
    size_t off = (size_t)(p0 + ty*4 + r) * Q + q0 + tx*4;
    float4 co = *(const float4*)&Cold[off];
    float4 v = { co.x - acc[r][0], co.y - acc[r][1], co.z - acc[r][2], co.w - acc[r][3] };
    *(float4*)&Cnew[off] = v;
  }
}

// ---------------- u1: bf16 MFMA NT GEMM (KK and Hb unified) ----------------
// C[i,j] = sum_k A[i,k]*B[j,k], 64x64 tile, K-slice of 448 (14 steps of 32).
// frag layout (16x16x32 bf16): A/B: lane holds M/N-row (lane&15), k=(lane>>4)*8+e
// C/D: col=lane&15, row=(lane>>4)*4+reg.  4 waves = 2x2 quadrants of 32x32.
__device__ __forceinline__ void nt64_mfma(
    const ushort* __restrict__ A, const ushort* __restrict__ B,
    int k0, float* __restrict__ dst, int ldc) {
  int tid = threadIdx.x;
  int lane = tid & 63;
  int wv = tid >> 6;
  int qr = wv >> 1, qc = wv & 1;
  int lr = lane & 15;
  int lk = (lane >> 4) << 3;
  const ushort* pa0 = A + (size_t)(qr * 32 + lr) * DM + k0 + lk;
  const ushort* pa1 = pa0 + 16 * DM;
  const ushort* pb0 = B + (size_t)(qc * 32 + lr) * DM + k0 + lk;
  const ushort* pb1 = pb0 + 16 * DM;
  f32x4 acc00 = {0.f, 0.f, 0.f, 0.f};
  f32x4 acc01 = acc00, acc10 = acc00, acc11 = acc00;
  bf16x8 a0 = *(const bf16x8*)pa0;
  bf16x8 a1 = *(const bf16x8*)pa1;
  bf16x8 b0 = *(const bf16x8*)pb0;
  bf16x8 b1 = *(const bf16x8*)pb1;
  #pragma unroll
  for (int s = 0; s < 14; ++s) {
    int sn = (s < 13) ? (s + 1) : s;     // last iter reloads (discarded)
    bf16x8 na0 = *(const bf16x8*)(pa0 + sn * 32);
    bf16x8 na1 = *(const bf16x8*)(pa1 + sn * 32);
    bf16x8 nb0 = *(const bf16x8*)(pb0 + sn * 32);
    bf16x8 nb1 = *(const bf16x8*)(pb1 + sn * 32);
    acc00 = __builtin_amdgcn_mfma_f32_16x16x32_bf16(a0, b0, acc00, 0, 0, 0);
    acc01 = __builtin_amdgcn_mfma_f32_16x16x32_bf16(a0, b1, acc01, 0, 0, 0);
    acc10 = __builtin_amdgcn_mfma_f32_16x16x32_bf16(a1, b0, acc10, 0, 0, 0);
    acc11 = __builtin_amdgcn_mfma_f32_16x16x32_bf16(a1, b1, acc11, 0, 0, 0);
    a0 = na0; a1 = na1; b0 = nb0; b1 = nb1;
  }
  int rb = (lane >> 4) * 4;
  float* d = dst + (size_t)(qr * 32 + rb) * ldc + qc * 32 + lr;
  #pragma unroll
  for (int r = 0; r < 4; ++r) {
    d[(size_t)r * ldc]             = acc00[r];
    d[(size_t)r * ldc + 16]        = acc01[r];
    d[(size_t)(r + 16) * ldc]      = acc10[r];
    d[(size_t)(r + 16) * ldc + 16] = acc11[r];
  }
}

__global__ __launch_bounds__(256) void u1_kernel(
    const ushort* __restrict__ nkb, const ushort* __restrict__ w1tb,
    float* __restrict__ KKsl, float* __restrict__ Hb_sl) {
  int job = blockIdx.x;
  if (job < 448) {
    // Hb: nk[512,3136] @ W1t^T -> [512,512]; 64 tiles x 7 k-slices
    int s = job % 7;
    int t = job / 7;
    int m0 = (t >> 3) * 64, n0 = (t & 7) * 64;
    nt64_mfma(nkb + (size_t)m0 * DM, w1tb + (size_t)n0 * DM, s * 448,
              Hb_sl + (size_t)s * 262144 + (size_t)m0 * 512 + n0, 512);
  } else {
    // KK: 36 chunk-pairs x 7 k-slices
    int j2 = job - 448;
    int p = j2 / 7, s = j2 % 7;
    int c = 0;
    while ((c + 1) * (c + 2) / 2 <= p) ++c;
    int j = p - c * (c + 1) / 2;
    nt64_mfma(nkb + (size_t)c * 64 * DM, nkb + (size_t)j * 64 * DM, s * 448,
              KKsl + ((size_t)p * 7 + s) * 4096, 64);
  }
}

// u2: KKf (sum 7) + Hbase (sum 7) + fused hred for chunk 0 (j<32768)
__global__ __launch_bounds__(256) void u2_kernel(
    const float* __restrict__ KKsl, const float* __restrict__ Hb_sl,
    float* __restrict__ KKf, float* __restrict__ Hbase,
    const float* __restrict__ b1,
    float* __restrict__ Hh, float* __restrict__ G, float* __restrict__ Gp) {
  int i = blockIdx.x * 256 + threadIdx.x;
  if (i < 147456) {
    int pair = i >> 12, e = i & 4095;
    float s = 0.f;
    #pragma unroll
    for (int t = 0; t < 7; ++t) s += KKsl[((size_t)pair * 7 + t) * 4096 + e];
    KKf[i] = s;
  } else {
    int j = i - 147456;   // < 262144
    float s = 0.f;
    #pragma unroll
    for (int t = 0; t < 7; ++t) s += Hb_sl[(size_t)t * 262144 + j];
    Hbase[j] = s;
    if (j < 32768) {      // chunk 0 rows: emit H/G/Gp directly
      Hh[j] = s;
      float g, gp;
      gelu_both(s + b1[j & 511], g, gp);
      G[j] = g; Gp[j] = gp;
    }
  }
}

// ---------------- hred ----------------
__device__ __forceinline__ void hred_body(
    int j, const float* __restrict__ Hb_c, const float* __restrict__ Hcorr, int nsl,
    const float* __restrict__ b1v,
    float* __restrict__ H, float* __restrict__ G, float* __restrict__ Gp) {
  float s = Hb_c[j];
  for (int t = 0; t < nsl; ++t) s -= Hcorr[(size_t)t * 32768 + j];
  H[j] = s;
  float g, gp;
  gelu_both(s + b1v[j & 511], g, gp);
  G[j] = g; Gp[j] = gp;
}

// ---------------- hs_corr / gelu2k jobs (proven R7) ----------------
__device__ __forceinline__ void hs_corr_job(
    const float* __restrict__ KK, const float* __restrict__ Ewj,
    float* __restrict__ dst, int bx, float* smem) {
  float* As = smem;
  float* Bs = smem + 4096;
  int tid = threadIdx.x;
  int n0 = bx * 64;
  {
    int m = tid >> 2, ib = (tid & 3) * 16;
    #pragma unroll
    for (int q = 0; q < 4; ++q) {
      float4 v = *(const float4*)(KK + m * 64 + ib + q * 4);
      As[(ib + q*4 + 0)*64 + m] = v.x;
      As[(ib + q*4 + 1)*64 + m] = v.y;
      As[(ib + q*4 + 2)*64 + m] = v.z;
      As[(ib + q*4 + 3)*64 + m] = v.w;
    }
    int kr = tid >> 4, nn = (tid & 15) * 4;
    #pragma unroll
    for (int q = 0; q < 4; ++q)
      *(float4*)&Bs[(kr + q*16)*64 + nn] = *(const float4*)(Ewj + (size_t)(kr + q*16) * DH + n0 + nn);
  }
  __syncthreads();
  int tx = tid & 15, ty = tid >> 4;
  float acc[4][4] = {{0.f}};
  #pragma unroll 16
  for (int kk = 0; kk < 64; ++kk) {
    float4 a = *(const float4*)&As[kk*64 + ty * 4];
    float4 b = *(const float4*)&Bs[kk*64 + tx * 4];
    MICRO_4x4
  }
  #pragma unroll
  for (int r = 0; r < 4; ++r) {
    float4 v = { acc[r][0], acc[r][1], acc[r][2], acc[r][3] };
    *(float4*)&dst[(ty*4 + r) * DH + n0 + tx*4] = v;
  }
}

__device__ __forceinline__ void gelu2k_job(
    const float* __restrict__ KKcc, const float* __restrict__ Ew,
    const float* __restrict__ H, const float* __restrict__ b1n,
    float* __restrict__ G2, int n0, float* smem) {
  float* KKs = smem;
  float* Ews = smem + 4096;
  int tid = threadIdx.x;
  #pragma unroll
  for (int q = 0; q < 4; ++q) {
    int e4 = q * 256 + tid;
    *(float4*)&KKs[e4 * 4] = *(const float4*)(KKcc + e4 * 4);
  }
  {
    int i = tid >> 2, c4 = (tid & 3) * 4;
    *(float4*)&Ews[i * 16 + c4] = *(const float4*)(Ew + (size_t)i * DH + n0 + c4);
  }
  __syncthreads();
  #pragma unroll
  for (int q = 0; q < 4; ++q) {
    int e = q * 256 + tid;
    int mrow = e >> 4, cc = e & 15;
    float corr = 0.f;
    #pragma unroll 16
    for (int i = 0; i < 64; ++i) corr += KKs[mrow * 64 + i] * Ews[i * 16 + cc];
    float xx = H[mrow * DH + n0 + cc] - corr + b1n[n0 + cc];
    G2[mrow * DH + n0 + cc] = gelu_only(xx);
  }
}

// ================= per-chunk pipeline kernels =================
// P3 for chunk 0 (upfront)
__global__ __launch_bounds__(256) void p3_kernel(
    const float* __restrict__ G, const float* __restrict__ W2c,
    float* __restrict__ Spred) {
  __shared__ float smem[8192];
  mm_nn_slice(G, DH, W2c, DM, Spred, DM, blockIdx.x % 49, blockIdx.x / 49, smem);
}

// kA: Dw + partial colsums (49 n-tiles x 8 row-groups = 392 blocks)
__global__ __launch_bounds__(256) void red_Db2(
    const float* __restrict__ Dp, const float* __restrict__ b2c,
    const float* __restrict__ V, float wc2,
    float* __restrict__ Dw, float* __restrict__ Dcs) {
  __shared__ float sm[256];
  int tid = threadIdx.x;
  int nt = blockIdx.x % 49, rg = blockIdx.x / 49;
  int col = nt * 64 + (tid & 63);
  int r0 = rg * 8 + (tid >> 6) * 2;
  float bb = b2c[col];
  float cs = 0.f;
  #pragma unroll
  for (int rr = 0; rr < 2; ++rr) {
    size_t off = (size_t)(r0 + rr) * DM + col;
    float s = 0.f;
    #pragma unroll
    for (int t = 0; t < 8; ++t) s += Dp[(size_t)t * 200704 + off];
    float d = wc2 * (s + bb - V[off]);
    Dw[off] = d;
    cs += d;
  }
  sm[tid] = cs;
  __syncthreads();
  if (tid < 128) sm[tid] += sm[tid + 128];
  __syncthreads();
  if (tid < 64) Dcs[(size_t)rg * DM + col] = sm[tid] + sm[tid + 64];
}

// kB: P4 E-slices (392) || W2n = W2c - G^T Dw (392)
__global__ __launch_bounds__(256) void p4w2_kernel(
    const float* __restrict__ Dw, const float* __restrict__ W2c,
    const float* __restrict__ G, float* __restrict__ SpE,
    float* __restrict__ W2n) {
  __shared__ float smem[8192];
  int b = blockIdx.x;
  if (b < 392) mm_nt_slice(Dw, DM, W2c, DM, SpE, DH, b & 7, b >> 3, smem);
  else {
    int li = b - 392;
    upd64_dev(G, DH, Dw, DM, W2c, W2n, li % 49, li / 49, smem);
  }
}

// kC: Ew + b1 update (128) || b2 finalize from Dcs (49)
__global__ __launch_bounds__(256) void ewb1_kernel(
    const float* __restrict__ Esl, const float* __restrict__ Gp,
    float* __restrict__ Ew, const float* __restrict__ b1old, float* __restrict__ b1new,
    const float* __restrict__ Dcs, const float* __restrict__ b2c,
    float* __restrict__ b2n) {
  __shared__ float smem[256];
  int tid = threadIdx.x;
  int b = blockIdx.x;
  if (b < 128) {
    int n0 = b * 4;
    int row = tid >> 2, c = tid & 3;
    int col = n0 + c;
    float s = 0.f;
    #pragma unroll
    for (int sl = 0; sl < 49; ++sl) s += Esl[(size_t)sl * 32768 + row * 512 + col];
    float ew = s * Gp[row * 512 + col];
    Ew[row * 512 + col] = ew;
    smem[tid] = ew;
    __syncthreads();
    for (int off = 128; off >= 4; off >>= 1) {
      if (tid < off) smem[tid] += smem[tid + off];
      __syncthreads();
    }
    if (tid < 4) b1new[n0 + tid] = b1old[n0 + tid] - smem[tid];
  } else {
    int jb = b - 128;                 // < 49
    if (tid < 64) {
      int col = jb * 64 + tid;
      float s = 0.f;
      #pragma unroll
      for (int rg = 0; rg < 8; ++rg) s += Dcs[(size_t)rg * DM + col];
      b2n[col] = b2c[col] - s;
    }
  }
}

// kD: G2 (32) || Hcorr j=ch for chunk ch+1 (8, if ch<7)
__global__ __launch_bounds__(256) void g2s_kernel(
    const float* __restrict__ KKf, int tri, int ch,
    const float* __restrict__ Ewst, const float* __restrict__ H,
    const float* __restrict__ b1n,
    float* __restrict__ G2, float* __restrict__ Hcorr) {
  __shared__ float smem[8192];
  int b = blockIdx.x;
  if (b < 32) {
    gelu2k_job(KKf + (size_t)(tri + ch) * 4096, Ewst + (size_t)ch * 32768,
               H, b1n, G2, b * 16, smem);
  } else {
    int bx = b - 32;
    int trin = (ch + 1) * (ch + 2) / 2;
    hs_corr_job(KKf + (size_t)(trin + ch) * 4096, Ewst + (size_t)ch * 32768,
                Hcorr + (size_t)ch * 32768, bx, smem);
  }
}

// kE: P7 Y-slices (392) || hred for chunk ch+1 (128, if ch<7)
__global__ __launch_bounds__(256) void p7h_kernel(
    const float* __restrict__ G2, const float* __restrict__ W2n,
    float* __restrict__ SpY,
    const float* __restrict__ Hbase_n, const float* __restrict__ Hcorr, int nsl,
    const float* __restrict__ b1n,
    float* __restrict__ H, float* __restrict__ Gnext, float* __restrict__ Gp) {
  __shared__ float smem[8192];
  int b = blockIdx.x;
  if (b < 392) {
    mm_nn_slice(G2, DH, W2n, DM, SpY, DM, b % 49, b / 49, smem);
  } else {
    int j = (b - 392) * 256 + threadIdx.x;   // < 32768
    hred_body(j, Hbase_n, Hcorr, nsl, b1n, H, Gnext, Gp);
  }
}

// kF: out rows (784) || P3 for chunk ch+1 (392, if ch<7)
//     || Hcorr slices for chunk ch+2, j<ch+1 (8*(ch+1), if ch<6)
__global__ __launch_bounds__(256) void redyp3_kernel(
    const float* __restrict__ SpY, const float* __restrict__ b2n,
    float* __restrict__ out, int t0,
    const float* __restrict__ Gnext, const float* __restrict__ W2n,
    float* __restrict__ Spred,
    const float* __restrict__ KKf, int ch,
    const float* __restrict__ Ewst, float* __restrict__ Hcorr) {
  __shared__ float smem[8192];
  int b = blockIdx.x;
  int tid = threadIdx.x;
  if (b < 784) {
    int j = b * 256 + tid;
    float s = 0.f;
    #pragma unroll
    for (int t = 0; t < 8; ++t) s += SpY[(size_t)t * 200704 + j];
    int i = j / DM;
    int d = j - i * DM;
    out[(size_t)t0 * DM + j] = s + b2n[d];
  } else if (b < 1176) {
    int b2 = b - 784;
    mm_nn_slice(Gnext, DH, W2n, DM, Spred, DM, b2 % 49, b2 / 49, smem);
  } else {
    int j2 = b - 1176;                 // < 8*(ch+1)
    int j = j2 >> 3, bx = j2 & 7;      // j <= ch
    int cn2 = ch + 2;
    int trin = cn2 * (cn2 + 1) / 2;
    hs_corr_job(KKf + (size_t)(trin + j) * 4096, Ewst + (size_t)j * 32768,
                Hcorr + (size_t)j * 32768, bx, smem);
  }
}

extern "C" void kernel_launch(void* const* d_in, const int* in_sizes, int n_in,
                              void* d_out, int out_size, void* d_ws, size_t ws_size,
                              hipStream_t stream) {
  const float* x  = (const float*)d_in[0];
  const float* wk = (const float*)d_in[1];
  const float* bk = (const float*)d_in[2];
  const float* wv = (const float*)d_in[3];
  const float* bv = (const float*)d_in[4];
  const float* sk = (const float*)d_in[5];
  const float* sv = (const float*)d_in[6];
  const float* W1 = (const float*)d_in[7];
  const float* b1 = (const float*)d_in[8];
  const float* W2 = (const float*)d_in[9];
  const float* b2 = (const float*)d_in[10];
  float* out = (float*)d_out;
  float* ws  = (float*)d_ws;

  // workspace layout (floats)
  ushort* nkb  = (ushort*)ws;              // 1,605,632 u16 (= 802,816 f footprint)
  ushort* w1tb = (ushort*)(ws + 802816);   // 1,605,632 u16
  float* nv    = ws + 1605632;             // 1,605,632
  float* W2A   = nv + 1605632;             // 1,605,632
  float* W2B   = W2A + 1605632;            // 1,605,632
  float* Spred = W2B + 1605632;            // 1,605,632
  float* SpY   = Spred + 1605632;          // 1,605,632
  float* Hb_sl = SpY + 1605632;            // 1,835,008 (7 x 262144)
  float* KKsl  = Hb_sl + 1835008;          // 1,032,192 (36 x 7 x 4096)
  float* Hbase = KKsl + 1032192;           // 262,144
  float* KKf   = Hbase + 262144;           // 147,456
  float* Hh    = KKf + 147456;             // 32,768
  float* GA    = Hh + 32768;               // 32,768
  float* GB    = GA + 32768;               // 32,768
  float* Gp    = GB + 32768;               // 32,768
  float* Dw    = Gp + 32768;               // 200,704
  float* Dcs   = Dw + 200704;              // 25,088 (8 x 3136)
  float* Ewst  = Dcs + 25088;              // 262,144 (8 x 32768)
  float* Hcorr = Ewst + 262144;            // 229,376 (7 x 32768)
  float* b1ws  = Hcorr + 229376;           // 512
  float* b2ws  = b1ws + 512;               // 3,136
  float* W2buf[2] = { W2A, W2B };
  float* Gbuf[2]  = { GA, GB };

  // weights[i] = ETA0 * ALPHA^i * (ALPHA^63 / ALPHA^i) = ETA0 * ALPHA^63 (constant)
  float wc2 = 2.0f * (float)(0.1 * pow(0.9, 63.0));

  conv_rms<<<1960, 256, 0, stream>>>(x, wk, bk, wv, bv, sk, sv, W1, w1tb, nkb, nv);
  u1_kernel<<<700, 256, 0, stream>>>(nkb, w1tb, KKsl, Hb_sl);
  u2_kernel<<<1600, 256, 0, stream>>>(KKsl, Hb_sl, KKf, Hbase, b1, Hh, Gbuf[0], Gp);
  p3_kernel<<<392, 256, 0, stream>>>(Gbuf[0], W2, Spred);

  for (int ch = 0; ch < 8; ++ch) {
    const float* V   = nv + (size_t)ch * 200704;
    const float* b1c = ch ? b1ws : b1;
    const float* b2c = ch ? b2ws : b2;
    const float* W2c = ch ? W2buf[(ch - 1) & 1] : W2;
    float* W2n  = W2buf[ch & 1];
    float* Gcur = Gbuf[ch & 1];
    float* Gnxt = Gbuf[(ch + 1) & 1];
    float* Ewc  = Ewst + (size_t)ch * 32768;
    int tri = ch * (ch + 1) / 2;

    // kA: Dw + partial colsums
    red_Db2<<<392, 256, 0, stream>>>(Spred, b2c, V, wc2, Dw, Dcs);
    // kB: E slices (into Spred) || W2n = W2c - G^T Dw
    p4w2_kernel<<<784, 256, 0, stream>>>(Dw, W2c, Gcur, Spred, W2n);
    // kC: Ew + b1 update || b2 finalize
    ewb1_kernel<<<177, 256, 0, stream>>>(Spred, Gp, Ewc, b1c, b1ws, Dcs, b2c, b2ws);
    // kD: G2 (overwrites Gcur) || Hcorr j=ch for chunk ch+1
    g2s_kernel<<<32 + (ch < 7 ? 8 : 0), 256, 0, stream>>>(
        KKf, tri, ch, Ewst, Hh, b1ws, Gcur, Hcorr);
    // kE: P7 Y-slices || hred for chunk ch+1
    p7h_kernel<<<392 + (ch < 7 ? 128 : 0), 256, 0, stream>>>(
        Gcur, W2n, SpY,
        Hbase + (size_t)(ch + 1) * 32768, Hcorr, ch + 1, b1ws, Hh, Gnxt, Gp);
    // kF: out rows || P3 for chunk ch+1 || Hcorr for chunk ch+2 (j<=ch)
    int gF = 784 + (ch < 7 ? 392 + (ch < 6 ? 8 * (ch + 1) : 0) : 0);
    redyp3_kernel<<<gF, 256, 0, stream>>>(
        SpY, b2ws, out, ch * 64, Gnxt, W2n, Spred, KKf, ch, Ewst, Hcorr);
  }
}

// Round 2
// 455.995 us; speedup vs baseline: 1.1661x; 1.1192x over previous
//
#include <hip/hip_runtime.h>
#include <math.h>

#define DM 3136
#define DH 512

typedef __attribute__((ext_vector_type(8))) short bf16x8;
typedef __attribute__((ext_vector_type(4))) float f32x4;

__device__ __forceinline__ ushort f2bf(float f) {
  union { float f; unsigned u; } v; v.f = f;
  unsigned r = v.u + 0x7FFFu + ((v.u >> 16) & 1u);
  return (ushort)(r >> 16);
}

// ---------------- gelu ----------------
__device__ __forceinline__ void gelu_both(float xx, float& g, float& gp) {
  const float c = 0.7978845608028654f;
  const float a = 0.044715f;
  float x2 = xx * xx;
  float u = c * (xx + a * xx * x2);
  float t = tanhf(u);
  g  = 0.5f * xx * (1.f + t);
  gp = 0.5f * (1.f + t) + 0.5f * xx * (1.f - t * t) * c * (1.f + 3.f * a * x2);
}
__device__ __forceinline__ float gelu_only(float xx) {
  const float c = 0.7978845608028654f;
  const float a = 0.044715f;
  float u = c * (xx + a * xx * xx * xx);
  return 0.5f * xx * (1.f + tanhf(u));
}

// ---------------- nt64 MFMA core: C[i,j] = sum_k A[i,k]*B[j,k] ----------------
// 64x64 tile, 4 waves = 2x2 quadrants of 32x32, 2x2 frags each.
// frag (16x16x32 bf16): A/B lane holds row (lane&15), k=(lane>>4)*8+e
// C/D: col=lane&15, row=(lane>>4)*4+reg.
__device__ __forceinline__ void nt64_core(
    const ushort* __restrict__ A, int lda,
    const ushort* __restrict__ B, int ldb,
    int ksteps, f32x4* acc) {
  int lane = threadIdx.x & 63;
  int wv = threadIdx.x >> 6;
  int qr = wv >> 1, qc = wv & 1;
  int lr = lane & 15;
  int lk = (lane >> 4) << 3;
  const ushort* pa0 = A + (size_t)(qr * 32 + lr) * lda + lk;
  const ushort* pa1 = pa0 + (size_t)16 * lda;
  const ushort* pb0 = B + (size_t)(qc * 32 + lr) * ldb + lk;
  const ushort* pb1 = pb0 + (size_t)16 * ldb;
  bf16x8 a0 = *(const bf16x8*)pa0;
  bf16x8 a1 = *(const bf16x8*)pa1;
  bf16x8 b0 = *(const bf16x8*)pb0;
  bf16x8 b1 = *(const bf16x8*)pb1;
  for (int s = 0; s < ksteps; ++s) {
    int sn = (s + 1 < ksteps) ? (s + 1) * 32 : s * 32;   // last iter reloads (discarded)
    bf16x8 na0 = *(const bf16x8*)(pa0 + sn);
    bf16x8 na1 = *(const bf16x8*)(pa1 + sn);
    bf16x8 nb0 = *(const bf16x8*)(pb0 + sn);
    bf16x8 nb1 = *(const bf16x8*)(pb1 + sn);
    acc[0] = __builtin_amdgcn_mfma_f32_16x16x32_bf16(a0, b0, acc[0], 0, 0, 0);
    acc[1] = __builtin_amdgcn_mfma_f32_16x16x32_bf16(a0, b1, acc[1], 0, 0, 0);
    acc[2] = __builtin_amdgcn_mfma_f32_16x16x32_bf16(a1, b0, acc[2], 0, 0, 0);
    acc[3] = __builtin_amdgcn_mfma_f32_16x16x32_bf16(a1, b1, acc[3], 0, 0, 0);
    a0 = na0; a1 = na1; b0 = nb0; b1 = nb1;
  }
}

__device__ __forceinline__ void nt64_store(const f32x4* acc, float* __restrict__ dst, int ldc) {
  int lane = threadIdx.x & 63, wv = threadIdx.x >> 6;
  int r0 = (wv >> 1) * 32 + ((lane >> 4) << 2);
  int c0 = (wv & 1) * 32 + (lane & 15);
  #pragma unroll
  for (int r = 0; r < 4; ++r) {
    dst[(size_t)(r0 + r) * ldc + c0]           = acc[0][r];
    dst[(size_t)(r0 + r) * ldc + c0 + 16]      = acc[1][r];
    dst[(size_t)(r0 + r + 16) * ldc + c0]      = acc[2][r];
    dst[(size_t)(r0 + r + 16) * ldc + c0 + 16] = acc[3][r];
  }
}

// ---------------- conv3x3 + RMSNorm + W1/W2 bf16 prep tails ----------------
__global__ __launch_bounds__(256) void conv_rms(
    const float* __restrict__ x,
    const float* __restrict__ wk, const float* __restrict__ bk,
    const float* __restrict__ wv, const float* __restrict__ bv,
    const float* __restrict__ sk, const float* __restrict__ sv,
    const float* __restrict__ W1, ushort* __restrict__ w1tb,
    const float* __restrict__ W2, ushort* __restrict__ W2b0, ushort* __restrict__ W2tb0,
    ushort* __restrict__ nkb, float* __restrict__ nv) {
  __shared__ float smem[4160];
  int tid = threadIdx.x;
  if (blockIdx.x >= 1960) {
    // W2 [512,3136] f32 -> W2b0 bf16 copy + W2tb0 [3136,512] bf16 transpose
    int t = blockIdx.x - 1960;           // 0..391
    int d0 = (t % 49) * 64, h0 = (t / 49) * 64;
    int c = tid & 63, rq = tid >> 6;
    #pragma unroll
    for (int q = 0; q < 16; ++q) {
      int r = q * 4 + rq;
      float v = W2[(size_t)(h0 + r) * DM + d0 + c];
      smem[r * 65 + c] = v;
      W2b0[(size_t)(h0 + r) * DM + d0 + c] = f2bf(v);
    }
    __syncthreads();
    #pragma unroll
    for (int q = 0; q < 16; ++q) {
      int r = q * 4 + rq;
      W2tb0[(size_t)(d0 + r) * DH + h0 + c] = f2bf(smem[c * 65 + r]);
    }
    return;
  }
  if (blockIdx.x >= 1568) {
    // transpose W1 [3136,512] f32 -> w1tb [512,3136] bf16
    int t = blockIdx.x - 1568;           // 0..391
    int d0 = (t % 49) * 64, h0 = (t / 49) * 64;
    int c = tid & 63, rq = tid >> 6;
    #pragma unroll
    for (int q = 0; q < 16; ++q) {
      int r = q * 4 + rq;
      smem[r * 65 + c] = W1[(size_t)(d0 + r) * 512 + h0 + c];
    }
    __syncthreads();
    #pragma unroll
    for (int q = 0; q < 16; ++q) {
      int r = q * 4 + rq;
      w1tb[(size_t)(h0 + r) * 3136 + d0 + c] = f2bf(smem[c * 65 + r]);
    }
    return;
  }
  float* swk = smem;
  float* swv = smem + 144;
  float* sb  = smem + 288;
  if (tid < 144) { swk[tid] = wk[tid]; swv[tid] = wv[tid]; }
  if (tid < 4) {
    sb[tid] = bk[tid]; sb[4 + tid] = bv[tid];
    sb[8 + tid] = sk[tid]; sb[12 + tid] = sv[tid];
  }
  __syncthreads();
  int idx = blockIdx.x * 256 + tid;
  int t = idx / 784, hw = idx - t * 784;
  int h = hw / 28, w = hw - h * 28;
  float ak[4], av[4];
  #pragma unroll
  for (int c = 0; c < 4; ++c) { ak[c] = sb[c]; av[c] = sb[4 + c]; }
  const float* xt = x + (size_t)t * DM;
  for (int kh = 0; kh < 3; ++kh) {
    int ih = h + kh - 1;
    if (ih < 0 || ih >= 28) continue;
    for (int kw = 0; kw < 3; ++kw) {
      int iw = w + kw - 1;
      if (iw < 0 || iw >= 28) continue;
      int base = (kh * 3 + kw) * 16;
      #pragma unroll
      for (int ci = 0; ci < 4; ++ci) {
        float xv = xt[ci * 784 + ih * 28 + iw];
        #pragma unroll
        for (int co = 0; co < 4; ++co) {
          ak[co] += xv * swk[base + ci * 4 + co];
          av[co] += xv * swv[base + ci * 4 + co];
        }
      }
    }
  }
  float mk = (ak[0]*ak[0] + ak[1]*ak[1] + ak[2]*ak[2] + ak[3]*ak[3]) * 0.25f + 1e-6f;
  float mv = (av[0]*av[0] + av[1]*av[1] + av[2]*av[2] + av[3]*av[3]) * 0.25f + 1e-6f;
  float ik = 1.f / sqrtf(mk), iv = 1.f / sqrtf(mv);
  ushort4 ok = { f2bf(ak[0]*ik*sb[8]), f2bf(ak[1]*ik*sb[9]),
                 f2bf(ak[2]*ik*sb[10]), f2bf(ak[3]*ik*sb[11]) };
  float4 ov = { av[0]*iv*sb[12], av[1]*iv*sb[13], av[2]*iv*sb[14], av[3]*iv*sb[15] };
  *(ushort4*)&nkb[(size_t)idx * 4] = ok;
  *(float4*)&nv[(size_t)idx * 4] = ov;
}

// ---------------- u1: KK + Hb slices (bf16 MFMA NT) ----------------
__global__ __launch_bounds__(256) void u1_kernel(
    const ushort* __restrict__ nkb, const ushort* __restrict__ w1tb,
    float* __restrict__ KKsl, float* __restrict__ Hb_sl) {
  f32x4 acc[4] = {{0.f,0.f,0.f,0.f},{0.f,0.f,0.f,0.f},{0.f,0.f,0.f,0.f},{0.f,0.f,0.f,0.f}};
  int job = blockIdx.x;
  if (job < 448) {
    // Hb: nk[512,3136] @ W1t^T -> [512,512]; 64 tiles x 7 k-slices
    int s = job % 7;
    int t = job / 7;
    int m0 = (t >> 3) * 64, n0 = (t & 7) * 64;
    nt64_core(nkb + (size_t)m0 * DM + s * 448, DM, w1tb + (size_t)n0 * DM + s * 448, DM, 14, acc);
    nt64_store(acc, Hb_sl + (size_t)s * 262144 + (size_t)m0 * 512 + n0, 512);
  } else {
    // KK: 36 chunk-pairs x 7 k-slices
    int j2 = job - 448;
    int p = j2 / 7, s = j2 % 7;
    int c = 0;
    while ((c + 1) * (c + 2) / 2 <= p) ++c;
    int j = p - c * (c + 1) / 2;
    nt64_core(nkb + (size_t)c * 64 * DM + s * 448, DM, nkb + (size_t)j * 64 * DM + s * 448, DM, 14, acc);
    nt64_store(acc, KKsl + ((size_t)p * 7 + s) * 4096, 64);
  }
}

// u2: KKf (sum 7) + Hbase (sum 7) + fused hred for chunk 0
__global__ __launch_bounds__(256) void u2_kernel(
    const float* __restrict__ KKsl, const float* __restrict__ Hb_sl,
    float* __restrict__ KKf, float* __restrict__ Hbase,
    const float* __restrict__ b1,
    float* __restrict__ Hh, ushort* __restrict__ Gb, ushort* __restrict__ Gtb,
    float* __restrict__ Gp) {
  int i = blockIdx.x * 256 + threadIdx.x;
  if (i < 147456) {
    int pair = i >> 12, e = i & 4095;
    float s = 0.f;
    #pragma unroll
    for (int t = 0; t < 7; ++t) s += KKsl[((size_t)pair * 7 + t) * 4096 + e];
    KKf[i] = s;
  } else {
    int j = i - 147456;   // < 262144
    float s = 0.f;
    #pragma unroll
    for (int t = 0; t < 7; ++t) s += Hb_sl[(size_t)t * 262144 + j];
    Hbase[j] = s;
    if (j < 32768) {      // chunk 0 rows: emit H/G/Gp directly
      Hh[j] = s;
      float g, gp;
      gelu_both(s + b1[j & 511], g, gp);
      Gb[j] = f2bf(g);
      Gtb[(j & 511) * 64 + (j >> 9)] = f2bf(g);
      Gp[j] = gp;
    }
  }
}

// ---------------- hred ----------------
__device__ __forceinline__ void hred_body(
    int j, const float* __restrict__ Hb_c, const float* __restrict__ Hcorr, int nsl,
    const float* __restrict__ b1v,
    float* __restrict__ Hh, ushort* __restrict__ Gb, ushort* __restrict__ Gtb,
    float* __restrict__ Gp) {
  float s = Hb_c[j];
  for (int t = 0; t < nsl; ++t) s -= Hcorr[(size_t)t * 32768 + j];
  Hh[j] = s;
  float g, gp;
  gelu_both(s + b1v[j & 511], g, gp);
  Gb[j] = f2bf(g);
  Gtb[(j & 511) * 64 + (j >> 9)] = f2bf(g);
  Gp[j] = gp;
}

// ---------------- hs_corr / gelu2k (fp32, small) ----------------
__device__ __forceinline__ void hs_corr_job(
    const float* __restrict__ KK, const float* __restrict__ Ewj,
    float* __restrict__ dst, int bx, float* smem) {
  float* As = smem;
  float* Bs = smem + 4096;
  int tid = threadIdx.x;
  int n0 = bx * 64;
  {
    int m = tid >> 2, ib = (tid & 3) * 16;
    #pragma unroll
    for (int q = 0; q < 4; ++q) {
      float4 v = *(const float4*)(KK + m * 64 + ib + q * 4);
      As[(ib + q*4 + 0)*64 + m] = v.x;
      As[(ib + q*4 + 1)*64 + m] = v.y;
      As[(ib + q*4 + 2)*64 + m] = v.z;
      As[(ib + q*4 + 3)*64 + m] = v.w;
    }
    int kr = tid >> 4, nn = (tid & 15) * 4;
    #pragma unroll
    for (int q = 0; q < 4; ++q)
      *(float4*)&Bs[(kr + q*16)*64 + nn] = *(const float4*)(Ewj + (size_t)(kr + q*16) * DH + n0 + nn);
  }
  __syncthreads();
  int tx = tid & 15, ty = tid >> 4;
  float acc[4][4] = {{0.f}};
  #pragma unroll 16
  for (int kk = 0; kk < 64; ++kk) {
    float4 a = *(const float4*)&As[kk*64 + ty * 4];
    float4 b = *(const float4*)&Bs[kk*64 + tx * 4];
    acc[0][0] += a.x*b.x; acc[0][1] += a.x*b.y; acc[0][2] += a.x*b.z; acc[0][3] += a.x*b.w;
    acc[1][0] += a.y*b.x; acc[1][1] += a.y*b.y; acc[1][2] += a.y*b.z; acc[1][3] += a.y*b.w;
    acc[2][0] += a.z*b.x; acc[2][1] += a.z*b.y; acc[2][2] += a.z*b.z; acc[2][3] += a.z*b.w;
    acc[3][0] += a.w*b.x; acc[3][1] += a.w*b.y; acc[3][2] += a.w*b.z; acc[3][3] += a.w*b.w;
  }
  #pragma unroll
  for (int r = 0; r < 4; ++r) {
    float4 v = { acc[r][0], acc[r][1], acc[r][2], acc[r][3] };
    *(float4*)&dst[(ty*4 + r) * DH + n0 + tx*4] = v;
  }
}

__device__ __forceinline__ void gelu2k_job(
    const float* __restrict__ KKcc, const float* __restrict__ Ew,
    const float* __restrict__ H, const float* __restrict__ b1n,
    ushort* __restrict__ G2b, int n0, float* smem) {
  float* KKs = smem;
  float* Ews = smem + 4096;
  int tid = threadIdx.x;
  #pragma unroll
  for (int q = 0; q < 4; ++q) {
    int e4 = q * 256 + tid;
    *(float4*)&KKs[e4 * 4] = *(const float4*)(KKcc + e4 * 4);
  }
  {
    int i = tid >> 2, c4 = (tid & 3) * 4;
    *(float4*)&Ews[i * 16 + c4] = *(const float4*)(Ew + (size_t)i * DH + n0 + c4);
  }
  __syncthreads();
  #pragma unroll
  for (int q = 0; q < 4; ++q) {
    int e = q * 256 + tid;
    int mrow = e >> 4, cc = e & 15;
    float corr = 0.f;
    #pragma unroll 16
    for (int i = 0; i < 64; ++i) corr += KKs[mrow * 64 + i] * Ews[i * 16 + cc];
    float xx = H[mrow * DH + n0 + cc] - corr + b1n[n0 + cc];
    G2b[mrow * DH + n0 + cc] = f2bf(gelu_only(xx));
  }
}

// ================= per-chunk pipeline kernels =================
// P3: Spred[64,3136] = G @ W2t^T (full K=512), 49 blocks
__global__ __launch_bounds__(256) void p3_kernel(
    const ushort* __restrict__ Gb, const ushort* __restrict__ W2tb,
    float* __restrict__ Spred) {
  f32x4 acc[4] = {{0.f,0.f,0.f,0.f},{0.f,0.f,0.f,0.f},{0.f,0.f,0.f,0.f},{0.f,0.f,0.f,0.f}};
  int n0 = blockIdx.x * 64;
  nt64_core(Gb, 512, W2tb + (size_t)n0 * 512, 512, 16, acc);
  nt64_store(acc, Spred + n0, DM);
}

// kA: Dw (bf16 + bf16^T) + partial colsums; Spred is a single slice now
__global__ __launch_bounds__(256) void red_Db2(
    const float* __restrict__ Sp, const float* __restrict__ b2c,
    const float* __restrict__ V, float wc2,
    ushort* __restrict__ Dwb, ushort* __restrict__ Dwtb, float* __restrict__ Dcs) {
  __shared__ float sm[256];
  int tid = threadIdx.x;
  int nt = blockIdx.x % 49, rg = blockIdx.x / 49;
  int col = nt * 64 + (tid & 63);
  int r0 = rg * 8 + (tid >> 6) * 2;
  float bb = b2c[col];
  float cs = 0.f;
  #pragma unroll
  for (int rr = 0; rr < 2; ++rr) {
    size_t off = (size_t)(r0 + rr) * DM + col;
    float d = wc2 * (Sp[off] + bb - V[off]);
    Dwb[off] = f2bf(d);
    Dwtb[(size_t)col * 64 + r0 + rr] = f2bf(d);
    cs += d;
  }
  sm[tid] = cs;
  __syncthreads();
  if (tid < 128) sm[tid] += sm[tid + 128];
  __syncthreads();
  if (tid < 64) Dcs[(size_t)rg * DM + col] = sm[tid] + sm[tid + 64];
}

// kB: E slices (56, MFMA) || W2 update (392, MFMA K=64) -> fp32 master + both bf16 shadows
__global__ __launch_bounds__(256) void p4w2_kernel(
    const ushort* __restrict__ Dwb, const ushort* __restrict__ Dwtb,
    const ushort* __restrict__ Gtb, const ushort* __restrict__ W2b_c,
    const float* __restrict__ W2c, float* __restrict__ W2n,
    ushort* __restrict__ W2b_n, ushort* __restrict__ W2tb_n,
    float* __restrict__ Esl) {
  f32x4 acc[4] = {{0.f,0.f,0.f,0.f},{0.f,0.f,0.f,0.f},{0.f,0.f,0.f,0.f},{0.f,0.f,0.f,0.f}};
  int b = blockIdx.x;
  if (b < 56) {
    // E[64,512] = Dwb[64,3136] @ W2b_c[512,3136]^T ; s-th K-slice of 448
    int s = b % 7, nt = b / 7;
    nt64_core(Dwb + s * 448, DM, W2b_c + (size_t)nt * 64 * DM + s * 448, DM, 14, acc);
    nt64_store(acc, Esl + (size_t)s * 32768 + nt * 64, 512);
  } else {
    // W2n[h,d] = W2c[h,d] - sum_m Gtb[h,m]*Dwtb[d,m]  (K=64)
    int li = b - 56;
    int d0 = (li % 49) * 64, h0 = (li / 49) * 64;
    nt64_core(Gtb + (size_t)h0 * 64, 64, Dwtb + (size_t)d0 * 64, 64, 2, acc);
    int lane = threadIdx.x & 63, wvv = threadIdx.x >> 6;
    int r0 = (wvv >> 1) * 32 + ((lane >> 4) << 2);
    int c0 = (wvv & 1) * 32 + (lane & 15);
    #pragma unroll
    for (int r = 0; r < 4; ++r) {
      #pragma unroll
      for (int p = 0; p < 4; ++p) {
        int h = h0 + r0 + r + ((p >> 1) ? 16 : 0);
        int d = d0 + c0 + ((p & 1) ? 16 : 0);
        size_t off = (size_t)h * DM + d;
        float w = W2c[off] - acc[p][r];
        W2n[off] = w;
        ushort wb = f2bf(w);
        W2b_n[off] = wb;
        W2tb_n[(size_t)d * DH + h] = wb;
      }
    }
  }
}

// kC: Ew + b1 update (128) || b2 finalize from Dcs (49)
__global__ __launch_bounds__(256) void ewb1_kernel(
    const float* __restrict__ Esl, const float* __restrict__ Gp,
    float* __restrict__ Ew, const float* __restrict__ b1old, float* __restrict__ b1new,
    const float* __restrict__ Dcs, const float* __restrict__ b2c,
    float* __restrict__ b2n) {
  __shared__ float smem[256];
  int tid = threadIdx.x;
  int b = blockIdx.x;
  if (b < 128) {
    int n0 = b * 4;
    int row = tid >> 2, c = tid & 3;
    int col = n0 + c;
    float s = 0.f;
    #pragma unroll
    for (int sl = 0; sl < 7; ++sl) s += Esl[(size_t)sl * 32768 + row * 512 + col];
    float ew = s * Gp[row * 512 + col];
    Ew[row * 512 + col] = ew;
    smem[tid] = ew;
    __syncthreads();
    for (int off = 128; off >= 4; off >>= 1) {
      if (tid < off) smem[tid] += smem[tid + off];
      __syncthreads();
    }
    if (tid < 4) b1new[n0 + tid] = b1old[n0 + tid] - smem[tid];
  } else {
    int jb = b - 128;                 // < 49
    if (tid < 64) {
      int col = jb * 64 + tid;
      float s = 0.f;
      #pragma unroll
      for (int rg = 0; rg < 8; ++rg) s += Dcs[(size_t)rg * DM + col];
      b2n[col] = b2c[col] - s;
    }
  }
}

// kD: G2 (32) || Hcorr j=ch for chunk ch+1 (8, if ch<7)
__global__ __launch_bounds__(256) void g2s_kernel(
    const float* __restrict__ KKf, int tri, int ch,
    const float* __restrict__ Ewst, const float* __restrict__ H,
    const float* __restrict__ b1n,
    ushort* __restrict__ G2b, float* __restrict__ Hcorr) {
  __shared__ float smem[8192];
  int b = blockIdx.x;
  if (b < 32) {
    gelu2k_job(KKf + (size_t)(tri + ch) * 4096, Ewst + (size_t)ch * 32768,
               H, b1n, G2b, b * 16, smem);
  } else {
    int bx = b - 32;
    int trin = (ch + 1) * (ch + 2) / 2;
    hs_corr_job(KKf + (size_t)(trin + ch) * 4096, Ewst + (size_t)ch * 32768,
                Hcorr + (size_t)ch * 32768, bx, smem);
  }
}

// kE: P7 Y -> out directly (49, MFMA full-K, +b2) || hred for chunk ch+1 (128, if ch<7)
__global__ __launch_bounds__(256) void p7h_kernel(
    const ushort* __restrict__ G2b, const ushort* __restrict__ W2tb,
    const float* __restrict__ b2n, float* __restrict__ out, int t0,
    const float* __restrict__ Hbase_n, const float* __restrict__ Hcorr, int nsl,
    const float* __restrict__ b1n,
    float* __restrict__ Hh, ushort* __restrict__ Gb_n, ushort* __restrict__ Gtb_n,
    float* __restrict__ Gp) {
  int b = blockIdx.x;
  if (b < 49) {
    f32x4 acc[4] = {{0.f,0.f,0.f,0.f},{0.f,0.f,0.f,0.f},{0.f,0.f,0.f,0.f},{0.f,0.f,0.f,0.f}};
    int n0 = b * 64;
    nt64_core(G2b, 512, W2tb + (size_t)n0 * 512, 512, 16, acc);
    int lane = threadIdx.x & 63, wvv = threadIdx.x >> 6;
    int r0 = (wvv >> 1) * 32 + ((lane >> 4) << 2);
    int c0 = (wvv & 1) * 32 + (lane & 15);
    #pragma unroll
    for (int r = 0; r < 4; ++r) {
      #pragma unroll
      for (int p = 0; p < 4; ++p) {
        int m = r0 + r + ((p >> 1) ? 16 : 0);
        int d = n0 + c0 + ((p & 1) ? 16 : 0);
        out[(size_t)(t0 + m) * DM + d] = acc[p][r] + b2n[d];
      }
    }
  } else {
    int j = (b - 49) * 256 + threadIdx.x;   // < 32768
    hred_body(j, Hbase_n, Hcorr, nsl, b1n, Hh, Gb_n, Gtb_n, Gp);
  }
}

// kF: P3 for chunk ch+1 (49) || Hcorr slices for chunk ch+2, j<ch+1 (8*(ch+1), if ch<6)
__global__ __launch_bounds__(256) void p3h_kernel(
    const ushort* __restrict__ Gnb, const ushort* __restrict__ W2tb,
    float* __restrict__ Spred,
    const float* __restrict__ KKf, int ch,
    const float* __restrict__ Ewst, float* __restrict__ Hcorr) {
  __shared__ float smem[8192];
  int b = blockIdx.x;
  if (b < 49) {
    f32x4 acc[4] = {{0.f,0.f,0.f,0.f},{0.f,0.f,0.f,0.f},{0.f,0.f,0.f,0.f},{0.f,0.f,0.f,0.f}};
    int n0 = b * 64;
    nt64_core(Gnb, 512, W2tb + (size_t)n0 * 512, 512, 16, acc);
    nt64_store(acc, Spred + n0, DM);
  } else {
    int j2 = b - 49;                   // < 8*(ch+1)
    int j = j2 >> 3, bx = j2 & 7;      // j <= ch
    int cn2 = ch + 2;
    int trin = cn2 * (cn2 + 1) / 2;
    hs_corr_job(KKf + (size_t)(trin + j) * 4096, Ewst + (size_t)j * 32768,
                Hcorr + (size_t)j * 32768, bx, smem);
  }
}

extern "C" void kernel_launch(void* const* d_in, const int* in_sizes, int n_in,
                              void* d_out, int out_size, void* d_ws, size_t ws_size,
                              hipStream_t stream) {
  const float* x  = (const float*)d_in[0];
  const float* wk = (const float*)d_in[1];
  const float* bk = (const float*)d_in[2];
  const float* wv = (const float*)d_in[3];
  const float* bv = (const float*)d_in[4];
  const float* sk = (const float*)d_in[5];
  const float* sv = (const float*)d_in[6];
  const float* W1 = (const float*)d_in[7];
  const float* b1 = (const float*)d_in[8];
  const float* W2 = (const float*)d_in[9];
  const float* b2 = (const float*)d_in[10];
  float* out = (float*)d_out;
  float* ws  = (float*)d_ws;

  // workspace layout (float units)
  ushort* nkb   = (ushort*)ws;                       // 802816 f
  ushort* w1tb  = (ushort*)(ws + 802816);            // 802816 f
  float* nv     = ws + 1605632;                      // 1605632
  float* W2A    = nv + 1605632;                      // 1605632
  float* W2B    = W2A + 1605632;                     // 1605632
  float* bf_base = W2B + 1605632;
  ushort* W2b0  = (ushort*)bf_base;                  // 802816 f
  ushort* W2tb0 = (ushort*)(bf_base + 802816);       // 802816 f
  ushort* W2bA  = (ushort*)(bf_base + 1605632);      // 802816 f
  ushort* W2bB  = (ushort*)(bf_base + 2408448);      // 802816 f
  ushort* W2tbA = (ushort*)(bf_base + 3211264);      // 802816 f
  ushort* W2tbB = (ushort*)(bf_base + 4014080);      // 802816 f
  float* Spred  = bf_base + 4816896;                 // 200704
  float* Esl    = Spred + 200704;                    // 229376 (7 x 32768)
  float* Hb_sl  = Esl + 229376;                      // 1835008 (7 x 262144)
  float* KKsl   = Hb_sl + 1835008;                   // 1032192 (36 x 7 x 4096)
  float* Hbase  = KKsl + 1032192;                    // 262144
  float* KKf    = Hbase + 262144;                    // 147456
  float* Hh     = KKf + 147456;                      // 32768
  float* Gp     = Hh + 32768;                        // 32768
  ushort* GbA   = (ushort*)(Gp + 32768);             // 16384 f
  ushort* GbB   = (ushort*)(Gp + 49152);             // 16384 f
  ushort* GtbA  = (ushort*)(Gp + 65536);             // 16384 f
  ushort* GtbB  = (ushort*)(Gp + 81920);             // 16384 f
  ushort* G2b   = (ushort*)(Gp + 98304);             // 16384 f
  ushort* Dwb   = (ushort*)(Gp + 114688);            // 100352 f
  ushort* Dwtb  = (ushort*)(Gp + 215040);            // 100352 f
  float* Dcs    = Gp + 315392;                       // 25088 (8 x 3136)
  float* Ewst   = Dcs + 25088;                       // 262144 (8 x 32768)
  float* Hcorr  = Ewst + 262144;                     // 229376 (7 x 32768)
  float* b1ws   = Hcorr + 229376;                    // 512
  float* b2ws   = b1ws + 512;                        // 3136

  float* W2buf[2]   = { W2A, W2B };
  ushort* W2bb[2]   = { W2bA, W2bB };
  ushort* W2tbb[2]  = { W2tbA, W2tbB };
  ushort* Gbb[2]    = { GbA, GbB };
  ushort* Gtbb[2]   = { GtbA, GtbB };

  // weights[i] = ETA0 * ALPHA^i * (ALPHA^63 / ALPHA^i) = ETA0 * ALPHA^63 (constant)
  float wc2 = 2.0f * (float)(0.1 * pow(0.9, 63.0));

  conv_rms<<<2352, 256, 0, stream>>>(x, wk, bk, wv, bv, sk, sv,
                                     W1, w1tb, W2, W2b0, W2tb0, nkb, nv);
  u1_kernel<<<700, 256, 0, stream>>>(nkb, w1tb, KKsl, Hb_sl);
  u2_kernel<<<1600, 256, 0, stream>>>(KKsl, Hb_sl, KKf, Hbase, b1, Hh, Gbb[0], Gtbb[0], Gp);
  p3_kernel<<<49, 256, 0, stream>>>(Gbb[0], W2tb0, Spred);

  for (int ch = 0; ch < 8; ++ch) {
    const float* V    = nv + (size_t)ch * 200704;
    const float* b1c  = ch ? b1ws : b1;
    const float* b2c  = ch ? b2ws : b2;
    const float* W2c  = ch ? W2buf[(ch - 1) & 1] : W2;
    const ushort* W2b_c = ch ? W2bb[(ch - 1) & 1] : W2b0;
    float* W2n    = W2buf[ch & 1];
    ushort* W2b_n  = W2bb[ch & 1];
    ushort* W2tb_n = W2tbb[ch & 1];
    int tri = ch * (ch + 1) / 2;

    // kA: Dw (bf16 both layouts) + partial colsums
    red_Db2<<<392, 256, 0, stream>>>(Spred, b2c, V, wc2, Dwb, Dwtb, Dcs);
    // kB: E slices || W2 update (fp32 master + bf16 shadows)
    p4w2_kernel<<<448, 256, 0, stream>>>(Dwb, Dwtb, Gtbb[ch & 1], W2b_c,
                                         W2c, W2n, W2b_n, W2tb_n, Esl);
    // kC: Ew + b1 update || b2 finalize
    ewb1_kernel<<<177, 256, 0, stream>>>(Esl, Gp, Ewst + (size_t)ch * 32768,
                                         b1c, b1ws, Dcs, b2c, b2ws);
    // kD: G2 (bf16) || Hcorr j=ch for chunk ch+1
    g2s_kernel<<<32 + (ch < 7 ? 8 : 0), 256, 0, stream>>>(
        KKf, tri, ch, Ewst, Hh, b1ws, G2b, Hcorr);
    // kE: P7 -> out directly || hred for chunk ch+1
    p7h_kernel<<<49 + (ch < 7 ? 128 : 0), 256, 0, stream>>>(
        G2b, W2tb_n, b2ws, out, ch * 64,
        Hbase + (size_t)(ch + 1) * 32768, Hcorr, ch + 1, b1ws,
        Hh, Gbb[(ch + 1) & 1], Gtbb[(ch + 1) & 1], Gp);
    // kF: P3 for chunk ch+1 || Hcorr for chunk ch+2 (j<=ch)
    if (ch < 7) {
      int gF = 49 + (ch < 6 ? 8 * (ch + 1) : 0);
      p3h_kernel<<<gF, 256, 0, stream>>>(
          Gbb[(ch + 1) & 1], W2tb_n, Spred, KKf, ch, Ewst, Hcorr);
    }
  }
}